// Round 11
// baseline (98.822 us; speedup 1.0000x reference)
//
#include <hip/hip_runtime.h>

#define N_ENT 400000
#define N_REL 500
#define N_TS 365
#define RANK 64
#define BATCH 256

typedef __attribute__((ext_vector_type(8))) __bf16 bf16x8;
typedef __attribute__((ext_vector_type(16))) float f32x16;
typedef __attribute__((ext_vector_type(4))) float f32x4;

// ---------------------------------------------------------------------------
// Kernel 1: fused prep + tail.  Grid = 365 blocks x 64 threads.
// ---------------------------------------------------------------------------
__global__ void prep_tail_kernel(const float* __restrict__ E0,
                                 const float* __restrict__ E1,
                                 const float* __restrict__ E2,
                                 const float* __restrict__ E3,
                                 const float* __restrict__ E4,
                                 const int* __restrict__ x,
                                 __bf16* __restrict__ Vbf,  // [BATCH][RANK]
                                 float* __restrict__ bias,  // [BATCH]
                                 float* __restrict__ out)
{
    const int b = blockIdx.x;
    const int k = threadIdx.x;

    const long long SCORES = (long long)BATCH * N_ENT;  // 102,400,000
    const int CP = (N_TS - 1) * RANK;                   // 23,296

    if (b == 364 && k == 0) out[SCORES] = 0.0f;  // cl_loss
    if (b < N_TS - 1) {
        const int idx = b * RANK + k;
        out[SCORES + 1 + 0LL * CP + idx] = E2[idx];
        out[SCORES + 1 + 1LL * CP + idx] = E3[idx];
        out[SCORES + 1 + 2LL * CP + idx] = E4[idx];
    }

    if (b < BATCH) {
        const int i = b;
        const int i0 = x[i * 4 + 0];
        const int i1 = x[i * 4 + 1];
        const int i3 = x[i * 4 + 3];

        const float lhs = E0[i0 * RANK + k];
        const float rel = E1[i1 * RANK + k];
        const float te  = E2[i3 * RANK + k];
        const float tr  = E3[i3 * RANK + k];

        // complex_mul(rel, comp_time) with half-width 32
        const int  kh = k & 31;
        const float a = E1[i1 * RANK + kh];
        const float bb = E1[i1 * RANK + 32 + kh];
        const float c = E4[i3 * RANK + kh];
        const float d = E4[i3 * RANK + 32 + kh];
        const float cm = (k < 32) ? (a * c + bb * d) : (a * d - bb * c);
        const float rel_ = rel + cm;

        const float v = 2.0f * (lhs * rel_ - te * tr);
        Vbf[i * RANK + k] = (__bf16)v;

        float rb = 2.0f * te * (lhs * tr + te * rel_);
        #pragma unroll
        for (int off = 32; off > 0; off >>= 1)
            rb += __shfl_down(rb, off, 64);
        if (k == 0) bias[i] = rb;
    }
}

// ---------------------------------------------------------------------------
// Kernel 2: scores = V @ E0^T + bias via mfma_f32_32x32x16_bf16.
//   Round-8 structure (block owns 256 cols; per M-tile: 8 MFMAs -> 32x256 LDS
//   transpose -> each wave stores ONE FULL ROW segment = 1 KB contiguous;
//   bijective XCD swizzle gives each XCD a contiguous column range)
//   + round-10's NON-TEMPORAL stores (write stream bypasses L2/L3, keeping
//   E0 L3-resident across replays).  With NT stores, DRAM burst locality
//   depends directly on store contiguity -> the 1 KB runs + XCD-local
//   streams should now pay where they were L2-hidden before.
//   C layout (verified): col=lane&31, row=(reg&3)+8*(reg>>2)+4*(lane>>5).
// ---------------------------------------------------------------------------
__global__ __launch_bounds__(256) void scores_mfma(
    const float* __restrict__ E0,
    const __bf16* __restrict__ Vbf,
    const float* __restrict__ bias,
    float* __restrict__ out)
{
    __shared__ __align__(16) float tile[32][256];  // 32 KiB
    __shared__ float sb[BATCH];                    // 1 KiB

    const int t    = threadIdx.x;
    const int lane = t & 63;
    const int wid  = t >> 6;             // 0..3
    const int l31  = lane & 31;
    const int h    = lane >> 5;          // 0/1
    const int khalf = h * 8;

    // ---- XCD-bijective swizzle (nwg = 1563 = 8*195 + 3) ----
    const int nwg = gridDim.x;
    const int qq  = nwg >> 3;            // 195
    const int rr  = nwg & 7;             // 3
    const int xcd = blockIdx.x & 7;
    const int idx = blockIdx.x >> 3;
    const int swz = (xcd < rr ? xcd * (qq + 1) : rr * (qq + 1) + (xcd - rr) * qq) + idx;

    const int colbase = swz * 256;
    const bool has_c1 = (colbase + 128) < N_ENT;   // false only for tail block

    sb[t] = bias[t];

    // ---- B fragments: 2 ctiles x 4 x (K=16), fp32 -> bf16 in-register ----
    bf16x8 bfrag[2][4];
    #pragma unroll
    for (int c = 0; c < 2; ++c) {
        if (c == 1 && !has_c1) break;
        const float* erow = E0 + (size_t)(colbase + c * 128 + wid * 32 + l31) * RANK;
        #pragma unroll
        for (int f = 0; f < 4; ++f) {
            const int kb = f * 16 + khalf;
            const float4 u0 = *reinterpret_cast<const float4*>(erow + kb);
            const float4 u1 = *reinterpret_cast<const float4*>(erow + kb + 4);
            bfrag[c][f][0] = (__bf16)u0.x;  bfrag[c][f][1] = (__bf16)u0.y;
            bfrag[c][f][2] = (__bf16)u0.z;  bfrag[c][f][3] = (__bf16)u0.w;
            bfrag[c][f][4] = (__bf16)u1.x;  bfrag[c][f][5] = (__bf16)u1.y;
            bfrag[c][f][6] = (__bf16)u1.z;  bfrag[c][f][7] = (__bf16)u1.w;
        }
    }

    #pragma unroll 1
    for (int mt = 0; mt < 8; ++mt) {
        const __bf16* arow = Vbf + (size_t)(mt * 32 + l31) * RANK + khalf;
        bf16x8 afrag[4];
        #pragma unroll
        for (int f = 0; f < 4; ++f)
            afrag[f] = *reinterpret_cast<const bf16x8*>(arow + f * 16);

        #pragma unroll
        for (int c = 0; c < 2; ++c) {
            if (c == 1 && !has_c1) break;
            f32x16 acc;
            #pragma unroll
            for (int j = 0; j < 16; ++j) acc[j] = 0.0f;
            #pragma unroll
            for (int f = 0; f < 4; ++f)
                acc = __builtin_amdgcn_mfma_f32_32x32x16_bf16(afrag[f], bfrag[c][f], acc, 0, 0, 0);

            // scatter into LDS (bank = l31, conflict-free)
            #pragma unroll
            for (int j = 0; j < 16; ++j) {
                const int row = (j & 3) + 8 * (j >> 2) + 4 * h;
                tile[row][c * 128 + wid * 32 + l31] = acc[j];
            }
        }
        __syncthreads();

        // ---- readback: wave w writes row q*4+w, 1 KB contiguous, NT ----
        const int m0 = mt * 32;
        const int cd = lane * 4;             // col dword within 256
        const bool sok = (colbase + cd) < N_ENT;
        #pragma unroll
        for (int qp = 0; qp < 8; ++qp) {
            const int row = qp * 4 + wid;
            const int m = m0 + row;
            f32x4 v = *reinterpret_cast<const f32x4*>(&tile[row][cd]);
            const float bv = sb[m];
            v.x += bv; v.y += bv; v.z += bv; v.w += bv;
            if (sok)
                __builtin_nontemporal_store(v,
                    reinterpret_cast<f32x4*>(&out[(size_t)m * N_ENT + colbase + cd]));
        }
        __syncthreads();
    }
}

// ---------------------------------------------------------------------------
extern "C" void kernel_launch(void* const* d_in, const int* in_sizes, int n_in,
                              void* d_out, int out_size, void* d_ws, size_t ws_size,
                              hipStream_t stream) {
    const float* E0 = (const float*)d_in[0];
    const float* E1 = (const float*)d_in[1];
    const float* E2 = (const float*)d_in[2];
    const float* E3 = (const float*)d_in[3];
    const float* E4 = (const float*)d_in[4];
    const int*   x  = (const int*)d_in[5];

    float* out = (float*)d_out;

    float*  bias = (float*)d_ws;                    // 1 KiB
    __bf16* Vbf  = (__bf16*)((char*)d_ws + 1024);   // 32 KiB

    prep_tail_kernel<<<N_TS, RANK, 0, stream>>>(E0, E1, E2, E3, E4, x, Vbf, bias, out);

    const int nblk = (N_ENT + 255) / 256;  // 1563 (last block: 128 cols)
    scores_mfma<<<nblk, 256, 0, stream>>>(E0, Vbf, bias, out);
}

// Round 12
// 97.654 us; speedup vs baseline: 1.0120x; 1.0120x over previous
//
#include <hip/hip_runtime.h>

#define N_ENT 400000
#define N_REL 500
#define N_TS 365
#define RANK 64
#define BATCH 256

typedef __attribute__((ext_vector_type(8))) __bf16 bf16x8;
typedef __attribute__((ext_vector_type(16))) float f32x16;
typedef __attribute__((ext_vector_type(4))) float f32x4;

// ---------------------------------------------------------------------------
// Kernel 1: fused prep + tail.  Grid = 365 blocks x 64 threads.
//   blocks 0..255 : batch prep -> Vbf (bf16) + bias
//   blocks 0..363 : copy row b of E2/E3/E4 into the tail outputs
//   block 364     : cl_loss = 0
// ---------------------------------------------------------------------------
__global__ void prep_tail_kernel(const float* __restrict__ E0,
                                 const float* __restrict__ E1,
                                 const float* __restrict__ E2,
                                 const float* __restrict__ E3,
                                 const float* __restrict__ E4,
                                 const int* __restrict__ x,
                                 __bf16* __restrict__ Vbf,  // [BATCH][RANK]
                                 float* __restrict__ bias,  // [BATCH]
                                 float* __restrict__ out)
{
    const int b = blockIdx.x;
    const int k = threadIdx.x;

    const long long SCORES = (long long)BATCH * N_ENT;  // 102,400,000
    const int CP = (N_TS - 1) * RANK;                   // 23,296

    if (b == 364 && k == 0) out[SCORES] = 0.0f;  // cl_loss
    if (b < N_TS - 1) {
        const int idx = b * RANK + k;
        out[SCORES + 1 + 0LL * CP + idx] = E2[idx];
        out[SCORES + 1 + 1LL * CP + idx] = E3[idx];
        out[SCORES + 1 + 2LL * CP + idx] = E4[idx];
    }

    if (b < BATCH) {
        const int i = b;
        const int i0 = x[i * 4 + 0];
        const int i1 = x[i * 4 + 1];
        const int i3 = x[i * 4 + 3];

        const float lhs = E0[i0 * RANK + k];
        const float rel = E1[i1 * RANK + k];
        const float te  = E2[i3 * RANK + k];
        const float tr  = E3[i3 * RANK + k];

        // complex_mul(rel, comp_time) with half-width 32
        const int  kh = k & 31;
        const float a = E1[i1 * RANK + kh];
        const float bb = E1[i1 * RANK + 32 + kh];
        const float c = E4[i3 * RANK + kh];
        const float d = E4[i3 * RANK + 32 + kh];
        const float cm = (k < 32) ? (a * c + bb * d) : (a * d - bb * c);
        const float rel_ = rel + cm;

        const float v = 2.0f * (lhs * rel_ - te * tr);
        Vbf[i * RANK + k] = (__bf16)v;

        float rb = 2.0f * te * (lhs * tr + te * rel_);
        #pragma unroll
        for (int off = 32; off > 0; off >>= 1)
            rb += __shfl_down(rb, off, 64);
        if (k == 0) bias[i] = rb;
    }
}

// ---------------------------------------------------------------------------
// Kernel 2: scores = V @ E0^T + bias via mfma_f32_32x32x16_bf16.
//   Round-5 structure + NON-TEMPORAL output stores (the round-10 winner).
//   NT stores keep the 410 MB touch-once write stream out of L2/L3, so E0
//   (102 MB) stays L3-resident across graph replays (round-1 FETCH evidence:
//   ~half of E0 was being refetched per replay due to write churn).
//   Loads stay cached (R4 showed NT loads regress).  Store run length and
//   XCD swizzle are neutral beyond 512 B (R8/R11).
//   C layout (verified): col=lane&31, row=(reg&3)+8*(reg>>2)+4*(lane>>5).
// ---------------------------------------------------------------------------
__global__ __launch_bounds__(256) void scores_mfma(
    const float* __restrict__ E0,
    const __bf16* __restrict__ Vbf,
    const float* __restrict__ bias,
    float* __restrict__ out)
{
    __shared__ __align__(16) float tile[2][32][128];  // 32 KiB ping-pong
    __shared__ float sbias[BATCH];                    // 1 KiB

    const int t    = threadIdx.x;
    const int lane = t & 63;
    const int wid  = t >> 6;             // 0..3
    const int l31  = lane & 31;
    const int h    = lane >> 5;          // 0/1
    const int colbase = blockIdx.x * 128;
    const int col  = colbase + wid * 32 + l31;
    const int khalf = h * 8;

    sbias[t] = bias[t];

    // ---- B fragments: 4 x (K=16) over K=64, fp32 -> bf16 in-register ----
    bf16x8 bfrag[4];
    const float* erow = E0 + (size_t)col * RANK;
    #pragma unroll
    for (int f = 0; f < 4; ++f) {
        const int kb = f * 16 + khalf;
        const float4 u0 = *reinterpret_cast<const float4*>(erow + kb);
        const float4 u1 = *reinterpret_cast<const float4*>(erow + kb + 4);
        bfrag[f][0] = (__bf16)u0.x;  bfrag[f][1] = (__bf16)u0.y;
        bfrag[f][2] = (__bf16)u0.z;  bfrag[f][3] = (__bf16)u0.w;
        bfrag[f][4] = (__bf16)u1.x;  bfrag[f][5] = (__bf16)u1.y;
        bfrag[f][6] = (__bf16)u1.z;  bfrag[f][7] = (__bf16)u1.w;
    }

    int p = 0;
    #pragma unroll 1
    for (int mt = 0; mt < 8; ++mt) {
        const __bf16* arow = Vbf + (size_t)(mt * 32 + l31) * RANK + khalf;

        f32x16 acc;
        #pragma unroll
        for (int j = 0; j < 16; ++j) acc[j] = 0.0f;

        #pragma unroll
        for (int f = 0; f < 4; ++f) {
            const bf16x8 afrag = *reinterpret_cast<const bf16x8*>(arow + f * 16);
            acc = __builtin_amdgcn_mfma_f32_32x32x16_bf16(afrag, bfrag[f], acc, 0, 0, 0);
        }

        // ---- write phase: scatter acc into row-major LDS tile ----
        #pragma unroll
        for (int j = 0; j < 16; ++j) {
            const int row = (j & 3) + 8 * (j >> 2) + 4 * h;
            tile[p][row][wid * 32 + l31] = acc[j];
        }
        __syncthreads();

        // ---- read phase: row-major f32x4 NT stores, bias folded in ----
        const int m0 = mt * 32;
        #pragma unroll
        for (int q = 0; q < 4; ++q) {
            const int row = q * 8 + (t >> 5);
            f32x4 v = *reinterpret_cast<const f32x4*>(&tile[p][row][(t & 31) * 4]);
            const float bv = sbias[m0 + row];
            v.x += bv; v.y += bv; v.z += bv; v.w += bv;
            __builtin_nontemporal_store(v,
                reinterpret_cast<f32x4*>(
                    &out[(size_t)(m0 + row) * N_ENT + colbase + (t & 31) * 4]));
        }
        p ^= 1;
        // no second barrier: next iteration writes the other buffer; reuse of
        // this buffer happens only after the NEXT barrier (hazard-checked).
    }
}

// ---------------------------------------------------------------------------
extern "C" void kernel_launch(void* const* d_in, const int* in_sizes, int n_in,
                              void* d_out, int out_size, void* d_ws, size_t ws_size,
                              hipStream_t stream) {
    const float* E0 = (const float*)d_in[0];
    const float* E1 = (const float*)d_in[1];
    const float* E2 = (const float*)d_in[2];
    const float* E3 = (const float*)d_in[3];
    const float* E4 = (const float*)d_in[4];
    const int*   x  = (const int*)d_in[5];

    float* out = (float*)d_out;

    float*  bias = (float*)d_ws;                    // 1 KiB
    __bf16* Vbf  = (__bf16*)((char*)d_ws + 1024);   // 32 KiB

    prep_tail_kernel<<<N_TS, RANK, 0, stream>>>(E0, E1, E2, E3, E4, x, Vbf, bias, out);

    const int nblk = N_ENT / 128;  // 3125
    scores_mfma<<<nblk, 256, 0, stream>>>(E0, Vbf, bias, out);
}